// Round 1
// baseline (1675.237 us; speedup 1.0000x reference)
//
#include <hip/hip_runtime.h>
#include <hip/hip_fp16.h>

// Problem constants (match reference)
#define N 128        // N_ASSETS
#define NZ 256       // 2n
#define MC 385       // constraint rows: 1 (eq) + 128 (G) + 256 (-I)
#define BATCH 32
#define N_ITERS 500

static constexpr float RHO_     = 0.1f;
static constexpr float SIGMA_   = 1e-6f;
static constexpr float RELAX_   = 1.6f;
static constexpr float ALPHA_   = 0.5f;
static constexpr float DELTA_   = 10.0f;
static constexpr float NEG_INF_ = -1e20f;
static constexpr float LN10_    = 2.302585092994046f;

// ---------------------------------------------------------------------------
// k_prep: y_pred = X@beta (written to out[4096..]), P1/P2 = ∓y_pred + p_term
// ---------------------------------------------------------------------------
__global__ __launch_bounds__(128) void k_prep(
    const float* __restrict__ X, const float* __restrict__ beta,
    const float* __restrict__ thE, const float* __restrict__ lg1p,
    float* __restrict__ out, float* __restrict__ P1, float* __restrict__ P2)
{
    __shared__ float xr[N];
    int b = blockIdx.x, i = threadIdx.x;
    xr[i] = X[b * N + i];
    __syncthreads();
    float acc = 0.f;
#pragma unroll 8
    for (int k = 0; k < N; ++k) acc = fmaf(xr[k], beta[k * N + i], acc);
    float gamma1 = expf(lg1p[0] * LN10_);                 // 10**log_gamma1
    float e = 1.0f / (1.0f + expf(-thE[i]));              // sigmoid(theta_E)
    float pt = ALPHA_ * gamma1 * e;
    out[BATCH * N + b * N + i] = acc;                     // y_pred output
    P1[b * N + i] = -acc + pt;
    P2[b * N + i] =  acc + pt;
}

// ---------------------------------------------------------------------------
// k_buildB: B = 2Q + 2*RHO*(A^T A + G^T G) + (SIGMA+RHO) I   (128x128 SPD)
//   Q = DELTA*V + (1-ALPHA)*gamma2*diag(d*d),  d = sigmoid(theta_D)
// ---------------------------------------------------------------------------
__global__ __launch_bounds__(128) void k_buildB(
    const float* __restrict__ V, const float* __restrict__ G,
    const float* __restrict__ A, const float* __restrict__ thD,
    const float* __restrict__ lg2p, float* __restrict__ B)
{
    __shared__ float ci[N];
    int i = blockIdx.x, j = threadIdx.x;
    ci[j] = G[j * N + i];                                 // column i of G
    __syncthreads();
    float acc = 0.f;
#pragma unroll 8
    for (int k = 0; k < N; ++k) acc = fmaf(ci[k], G[k * N + j], acc);
    float v = 2.0f * DELTA_ * V[i * N + j] + 2.0f * RHO_ * (A[i] * A[j] + acc);
    if (i == j) {
        float gamma2 = expf(lg2p[0] * LN10_);
        float di = 1.0f / (1.0f + expf(-thD[i]));
        v += 2.0f * (1.0f - ALPHA_) * gamma2 * di * di + (SIGMA_ + RHO_);
    }
    B[i * N + j] = v;
}

// ---------------------------------------------------------------------------
// k_invert: H = B^{-1} via Gauss-Jordan (no pivoting; B is SPD). One block.
// ---------------------------------------------------------------------------
__global__ __launch_bounds__(1024) void k_invert(
    const float* __restrict__ B, float* __restrict__ H)
{
    __shared__ float MM[N][N + 4];
    __shared__ float II[N][N + 4];
    __shared__ float colk[N];
    int tid = threadIdx.x;
    for (int idx = tid; idx < N * N; idx += 1024) {
        int i = idx >> 7, j = idx & 127;
        MM[i][j] = B[idx];
        II[i][j] = (i == j) ? 1.0f : 0.0f;
    }
    __syncthreads();
    for (int k = 0; k < N; ++k) {
        if (tid < N) colk[tid] = MM[tid][k];
        __syncthreads();
        float pinv = 1.0f / colk[k];
        if (tid < 2 * N) {
            if (tid < N) MM[k][tid]     *= pinv;
            else         II[k][tid - N] *= pinv;
        }
        __syncthreads();
        int c  = tid & 255;       // column (0..255 across MM|II)
        int ig = tid >> 8;        // row group 0..3
        float rk = (c < N) ? MM[k][c] : II[k][c - N];
        for (int i = ig * 32; i < ig * 32 + 32; ++i) {
            if (i == k) continue;
            float f = colk[i];
            if (c < N) MM[i][c]     = fmaf(-f, rk, MM[i][c]);
            else       II[i][c - N] = fmaf(-f, rk, II[i][c - N]);
        }
        __syncthreads();
    }
    for (int idx = tid; idx < N * N; idx += 1024)
        H[idx] = II[idx >> 7][idx & 127];
}

// ---------------------------------------------------------------------------
// k_admm: 500 ADMM iterations. One block per batch chain, all matrices in LDS.
//   sum/diff decomposition: M^{-1}[r1;r2] -> xs = (r1+r2)/(SIGMA+RHO),
//   xd = H @ (r1-r2), x1 = (xs+xd)/2, x2 = (xs-xd)/2.  Note x_t1-x_t2 = xd.
// ---------------------------------------------------------------------------
__global__ __launch_bounds__(256) void k_admm(
    const float* __restrict__ Hg, const float* __restrict__ G,
    const float* __restrict__ A, const float* __restrict__ bvec,
    const float* __restrict__ hvec, const float* __restrict__ P1,
    const float* __restrict__ P2, float* __restrict__ out)
{
    __shared__ float  Hs[N][N + 4];       // 67.6 KB, rows padded (132 floats)
    __shared__ __half Gs[N][N + 8];       // 34.8 KB, G  (exact: entries 0/-1)
    __shared__ __half Gts[N][N + 8];      // 34.8 KB, G^T
    __shared__ float As[N], hs[N], p1s[N], p2s[N];
    __shared__ float x1[N], x2[N];
    __shared__ float zv[MC], yv[MC], tv[MC];
    __shared__ float dv[N], sv[N], xd[N], xt1[N], xt2[N];
    __shared__ float pp0[N], pp1[N];
    __shared__ float zt0s;

    int tid = threadIdx.x;
    int b = blockIdx.x;

    for (int idx = tid; idx < N * N; idx += 256) {
        int i = idx >> 7, j = idx & 127;
        float g = G[idx];
        Hs[i][j]  = Hg[idx];
        Gs[i][j]  = __float2half(g);
        Gts[j][i] = __float2half(g);
    }
    if (tid < N) {
        As[tid]  = A[tid];
        hs[tid]  = hvec[tid];
        p1s[tid] = P1[b * N + tid];
        p2s[tid] = P2[b * N + tid];
        x1[tid] = 0.f; x2[tid] = 0.f;
    }
    for (int m = tid; m < MC; m += 256) { zv[m] = 0.f; yv[m] = 0.f; }
    float b0 = bvec[0];
    __syncthreads();

    const float inv_sr  = 1.0f / (SIGMA_ + RHO_);
    const float inv_rho = 1.0f / RHO_;
    const int i0 = tid & 127;     // row index
    const int hf = tid >> 7;      // j-half: 0 or 1
    const int jb = hf * 64;

    for (int it = 0; it < N_ITERS; ++it) {
        // phase 1: t = RHO*z - y
        for (int m = tid; m < MC; m += 256) tv[m] = fmaf(RHO_, zv[m], -yv[m]);
        __syncthreads();
        // phase 2: g = A^T t0 + G^T t_g  (2-way j-split partials)
        {
            float acc = 0.f;
#pragma unroll
            for (int j = 0; j < 64; ++j)
                acc = fmaf(__half2float(Gts[i0][jb + j]), tv[1 + jb + j], acc);
            if (hf == 0) acc = fmaf(As[i0], tv[0], acc);
            (hf ? pp1 : pp0)[i0] = acc;
        }
        __syncthreads();
        // phase 3: rhs halves -> sum / diff
        if (tid < N) {
            float g  = pp0[tid] + pp1[tid];
            float r1 = fmaf(SIGMA_, x1[tid], -p1s[tid]) + g - tv[129 + tid];
            float r2 = fmaf(SIGMA_, x2[tid], -p2s[tid]) - g - tv[257 + tid];
            sv[tid] = r1 + r2;
            dv[tid] = r1 - r2;
        }
        __syncthreads();
        // phase 4: xd partials = H @ d
        {
            float acc = 0.f;
#pragma unroll
            for (int j = 0; j < 64; ++j)
                acc = fmaf(Hs[i0][jb + j], dv[jb + j], acc);
            (hf ? pp1 : pp0)[i0] = acc;
        }
        __syncthreads();
        // phase 5: combine -> xd, x_t
        if (tid < N) {
            float xdv = pp0[tid] + pp1[tid];
            float xs  = sv[tid] * inv_sr;
            xd[tid]  = xdv;
            xt1[tid] = 0.5f * (xs + xdv);
            xt2[tid] = 0.5f * (xs - xdv);
        }
        __syncthreads();
        // phase 6: z_t rows 1..128 partials = G @ xd ; z_t[0] = dot(A, xd)
        {
            float acc = 0.f;
#pragma unroll
            for (int j = 0; j < 64; ++j)
                acc = fmaf(__half2float(Gs[i0][jb + j]), xd[jb + j], acc);
            (hf ? pp1 : pp0)[i0] = acc;
        }
        if (tid < 64) {
            float pa = fmaf(As[tid], xd[tid], As[tid + 64] * xd[tid + 64]);
#pragma unroll
            for (int s = 32; s > 0; s >>= 1) pa += __shfl_down(pa, s, 64);
            if (tid == 0) zt0s = pa;
        }
        __syncthreads();
        // phase 7: over-relax, clip, dual update; x update
        for (int m = tid; m < MC; m += 256) {
            float zt, up, lo = NEG_INF_;
            if (m == 0)       { zt = zt0s; lo = b0; up = b0; }
            else if (m <= N)  { zt = pp0[m - 1] + pp1[m - 1]; up = hs[m - 1]; }
            else {
                int q = m - (N + 1);
                zt = -((q < N) ? xt1[q] : xt2[q - N]);
                up = 0.f;
            }
            float zr = fmaf(RELAX_, zt, (1.0f - RELAX_) * zv[m]);
            float zn = fminf(fmaxf(fmaf(yv[m], inv_rho, zr), lo), up);
            yv[m] = fmaf(RHO_, zr - zn, yv[m]);
            zv[m] = zn;
        }
        if (tid < N) {
            x1[tid] = fmaf(RELAX_, xt1[tid], (1.0f - RELAX_) * x1[tid]);
            x2[tid] = fmaf(RELAX_, xt2[tid], (1.0f - RELAX_) * x2[tid]);
        }
        __syncthreads();
    }
    if (tid < N) out[b * N + tid] = x1[tid] - x2[tid];   // z = u1 - u2
}

// ---------------------------------------------------------------------------
extern "C" void kernel_launch(void* const* d_in, const int* in_sizes, int n_in,
                              void* d_out, int out_size, void* d_ws, size_t ws_size,
                              hipStream_t stream) {
    (void)in_sizes; (void)n_in; (void)out_size; (void)ws_size;
    const float* X    = (const float*)d_in[0];
    const float* V    = (const float*)d_in[1];
    const float* beta = (const float*)d_in[2];
    const float* thE  = (const float*)d_in[3];
    const float* thD  = (const float*)d_in[4];
    const float* lg1  = (const float*)d_in[5];
    const float* lg2  = (const float*)d_in[6];
    const float* A    = (const float*)d_in[7];
    const float* bv   = (const float*)d_in[8];
    const float* G    = (const float*)d_in[9];
    const float* hv   = (const float*)d_in[10];
    float* out = (float*)d_out;
    float* ws  = (float*)d_ws;
    float* Bm = ws;                // 16384 floats
    float* Hm = ws + 16384;        // 16384 floats
    float* P1 = ws + 32768;        // 4096 floats
    float* P2 = ws + 36864;        // 4096 floats

    hipLaunchKernelGGL(k_prep,   dim3(BATCH), dim3(128),  0, stream, X, beta, thE, lg1, out, P1, P2);
    hipLaunchKernelGGL(k_buildB, dim3(N),     dim3(128),  0, stream, V, G, A, thD, lg2, Bm);
    hipLaunchKernelGGL(k_invert, dim3(1),     dim3(1024), 0, stream, Bm, Hm);
    hipLaunchKernelGGL(k_admm,   dim3(BATCH), dim3(256),  0, stream, Hm, G, A, bv, hv, P1, P2, out);
}